// Round 2
// baseline (103.014 us; speedup 1.0000x reference)
//
#include <hip/hip_runtime.h>

// Least_Squares_weight: batched weighted 2-D Kabsch with GLOBAL weight sum.
// Closed-form 2x2 rotation: theta = atan2(H01-H10, H00+H11).
// Per-batch sums (14): s1=Σw, s2=Σw², sa=Σw·a, sb=Σw·b,
//                      saw2=Σw²·a, sbw2=Σw²·b, M=Σw²·a b^T
// H = M - saw2⊗G_B - G_A⊗sbw2 + s2·G_A⊗G_B,  G = sa/ws (ws = GLOBAL Σw).
//
// R2: 16 lanes per batch (4 batches per wave) -> butterfly reduce is only
// 4 rounds x 14 shuffles per 4 batches (vs 6 x 14 per 1 batch in R1).
// Partials stored AoS [b][16] so stores/loads are float4.

#define NUMPTS 256

// slot layout per batch (16 floats):
// 0:s2 1:sax 2:say 3:sbx | 4:sby 5:tax 6:tay 7:tbx | 8:tby 9:m00 10:m01 11:m10 | 12:m11 13:s1 14:- 15:-

// ---------------- kernel 1: per-batch partial sums ------------------------
__global__ __launch_bounds__(256) void k_partials(
    const float* __restrict__ A, const float* __restrict__ Bp,
    const float* __restrict__ W, float* __restrict__ P, int Bn)
{
    const int lane = threadIdx.x & 63;
    const int wave = threadIdx.x >> 6;
    const int t = lane & 15;                       // sub-lane within 16-group
    const int b = blockIdx.x * 16 + wave * 4 + (lane >> 4);

    const float4* A4 = (const float4*)(A + (size_t)b * (NUMPTS * 2));
    const float4* B4 = (const float4*)(Bp + (size_t)b * (NUMPTS * 2));
    const float4* W4 = (const float4*)(W + (size_t)b * NUMPTS);

    // hoist all 20 loads (fully coalesced: lane t reads 32B contiguous A/B)
    float4 wv[4], av[8], bv[8];
#pragma unroll
    for (int j = 0; j < 4; ++j) {
        wv[j]       = W4[t + 16 * j];
        av[2*j]     = A4[2*t + 32*j];
        av[2*j + 1] = A4[2*t + 32*j + 1];
        bv[2*j]     = B4[2*t + 32*j];
        bv[2*j + 1] = B4[2*t + 32*j + 1];
    }

    float s1 = 0.f, s2 = 0.f, sax = 0.f, say = 0.f, sbx = 0.f, sby = 0.f;
    float tax = 0.f, tay = 0.f, tbx = 0.f, tby = 0.f;
    float m00 = 0.f, m01 = 0.f, m10 = 0.f, m11 = 0.f;

#define ACC(ax, ay, bx, by, w) do {                         \
        float _w = (w), _w2 = _w * _w;                      \
        s1 += _w;  s2 += _w2;                               \
        sax += _w * (ax);  say += _w * (ay);                \
        sbx += _w * (bx);  sby += _w * (by);                \
        float _wax = _w2 * (ax), _way = _w2 * (ay);         \
        tax += _wax;  tay += _way;                          \
        tbx += _w2 * (bx);  tby += _w2 * (by);              \
        m00 += _wax * (bx);  m01 += _wax * (by);            \
        m10 += _way * (bx);  m11 += _way * (by);            \
    } while (0)

#pragma unroll
    for (int j = 0; j < 4; ++j) {
        float4 w4 = wv[j];
        float4 a0 = av[2*j], a1 = av[2*j + 1];
        float4 b0 = bv[2*j], b1 = bv[2*j + 1];
        ACC(a0.x, a0.y, b0.x, b0.y, w4.x);
        ACC(a0.z, a0.w, b0.z, b0.w, w4.y);
        ACC(a1.x, a1.y, b1.x, b1.y, w4.z);
        ACC(a1.z, a1.w, b1.z, b1.w, w4.w);
    }
#undef ACC

    // butterfly reduce within each 16-lane group (xor 8,4,2,1)
#pragma unroll
    for (int m = 8; m >= 1; m >>= 1) {
        s1  += __shfl_xor(s1, m);   s2  += __shfl_xor(s2, m);
        sax += __shfl_xor(sax, m);  say += __shfl_xor(say, m);
        sbx += __shfl_xor(sbx, m);  sby += __shfl_xor(sby, m);
        tax += __shfl_xor(tax, m);  tay += __shfl_xor(tay, m);
        tbx += __shfl_xor(tbx, m);  tby += __shfl_xor(tby, m);
        m00 += __shfl_xor(m00, m);  m01 += __shfl_xor(m01, m);
        m10 += __shfl_xor(m10, m);  m11 += __shfl_xor(m11, m);
    }

    if (t == 0) {
        float4* Pv = (float4*)P + (size_t)b * 4;
        Pv[0] = make_float4(s2,  sax, say, sbx);
        Pv[1] = make_float4(sby, tax, tay, tbx);
        Pv[2] = make_float4(tby, m00, m01, m10);
        Pv[3] = make_float4(m11, s1,  0.f, 0.f);
    }
}

// ---------------- kernel 2: deterministic global ws = Σ_b s1[b] ----------
__global__ __launch_bounds__(1024) void k_ws(
    const float* __restrict__ P, float* __restrict__ wsum, int Bn)
{
    const float4* Pv = (const float4*)P;
    float acc = 0.f;
    for (int i = threadIdx.x; i < Bn; i += 1024)
        acc += Pv[(size_t)i * 4 + 3].y;            // slot 13 = s1
#pragma unroll
    for (int m = 32; m >= 1; m >>= 1) acc += __shfl_xor(acc, m);

    __shared__ float sm[16];
    if ((threadIdx.x & 63) == 0) sm[threadIdx.x >> 6] = acc;
    __syncthreads();
    if (threadIdx.x == 0) {
        float v = 0.f;
#pragma unroll
        for (int i = 0; i < 16; ++i) v += sm[i];
        wsum[0] = v;
    }
}

// ---------------- kernel 3: per-batch closed-form solve -------------------
__global__ __launch_bounds__(256) void k_final(
    const float* __restrict__ P, const float* __restrict__ wsum,
    float* __restrict__ out, int Bn)
{
    const int b = blockIdx.x * 256 + threadIdx.x;
    if (b >= Bn) return;
    const size_t Bs = (size_t)Bn;

    const float4* Pv = (const float4*)P + (size_t)b * 4;
    const float4 p0 = Pv[0], p1 = Pv[1], p2 = Pv[2], p3 = Pv[3];

    const float s2  = p0.x;
    const float sax = p0.y, say = p0.z;
    const float sbx = p0.w, sby = p1.x;
    const float tax = p1.y, tay = p1.z;
    const float tbx = p1.w, tby = p2.x;
    const float m00 = p2.y, m01 = p2.z;
    const float m10 = p2.w, m11 = p3.x;

    const float inv = 1.0f / wsum[0];
    const float GAx = sax * inv, GAy = say * inv;
    const float GBx = sbx * inv, GBy = sby * inv;

    const float H00 = m00 - tax * GBx - GAx * tbx + s2 * GAx * GBx;
    const float H01 = m01 - tax * GBy - GAx * tby + s2 * GAx * GBy;
    const float H10 = m10 - tay * GBx - GAy * tbx + s2 * GAy * GBx;
    const float H11 = m11 - tay * GBy - GAy * tby + s2 * GAy * GBy;

    const float cp = H00 + H11;          // ~ r*cos(theta)
    const float sp = H01 - H10;          // ~ r*sin(theta)
    const float theta = atan2f(sp, cp);

    const float r = sqrtf(cp * cp + sp * sp);
    const float c = cp / r, s = sp / r;  // R = [[c,-s],[s,c]]

    const float tx = GBx - (c * GAx - s * GAy);
    const float ty = GBy - (s * GAx + c * GAy);

    out[0 * Bs + b] = theta;
    out[1 * Bs + b] = tx;
    out[2 * Bs + b] = ty;
}

// ---------------- launch ---------------------------------------------------
extern "C" void kernel_launch(void* const* d_in, const int* in_sizes, int n_in,
                              void* d_out, int out_size, void* d_ws, size_t ws_size,
                              hipStream_t stream) {
    const float* A  = (const float*)d_in[0];   // pstA  [B,256,2]
    const float* Bp = (const float*)d_in[1];   // pstB  [B,256,2]
    const float* W  = (const float*)d_in[2];   // weight[B,256,1]
    const int Bn = in_sizes[2] / NUMPTS;       // 65536

    float* P    = (float*)d_ws;                // [Bn][16] floats = 4 MiB
    float* wsum = P + (size_t)Bn * 16;         // +1 scalar
    float* out  = (float*)d_out;               // theta[Bn], tx[Bn], ty[Bn]

    hipLaunchKernelGGL(k_partials, dim3(Bn / 16), dim3(256), 0, stream,
                       A, Bp, W, P, Bn);
    hipLaunchKernelGGL(k_ws, dim3(1), dim3(1024), 0, stream, P, wsum, Bn);
    hipLaunchKernelGGL(k_final, dim3(Bn / 256), dim3(256), 0, stream,
                       P, wsum, out, Bn);
}

// Round 3
// 88.854 us; speedup vs baseline: 1.1594x; 1.1594x over previous
//
#include <hip/hip_runtime.h>

// Least_Squares_weight: batched weighted 2-D Kabsch with GLOBAL weight sum.
// Closed-form 2x2 rotation: theta = atan2(H01-H10, H00+H11).
//   cp = H00+H11 = mp - (tax*GBx+tay*GBy) - (GAx*tbx+GAy*tby) + s2*(GA.GB)
//   sp = H01-H10 = mm - (tax*GBy-tay*GBx) - (GAx*tby-GAy*tbx) + s2*(GAxGB)_z
// Per-batch sums (12): s1=Σw, s2=Σw², sa=Σw·a, sb=Σw·b, ta=Σw²·a, tb=Σw²·b,
//   mp=Σw²·(a·b), mm=Σw²·(a×b)_z
// G_A = sa/ws, G_B = sb/ws with ws = GLOBAL Σ over all batches of s1.
//
// R3: 16 lanes per batch, all 20 float4 loads hoisted (VGPR cap 128 via
// launch_bounds), 12 reduced quantities, dense S1 array so k_ws reads
// 256 KB contiguous (R2's 4MB strided k_ws read was a ~27us regression).

#define NUMPTS 256

// P record per batch (12 floats = 3 float4):
// 0:s2 1:sax 2:say 3:sbx | 4:sby 5:tax 6:tay 7:tbx | 8:tby 9:mp 10:mm 11:s1

// ---------------- kernel 1: per-batch partial sums ------------------------
__global__ __launch_bounds__(256, 4) void k_partials(
    const float* __restrict__ A, const float* __restrict__ Bp,
    const float* __restrict__ W, float* __restrict__ P,
    float* __restrict__ S1, int Bn)
{
    const int lane = threadIdx.x & 63;
    const int wave = threadIdx.x >> 6;
    const int t = lane & 15;                       // sub-lane within 16-group
    const int b = blockIdx.x * 16 + wave * 4 + (lane >> 4);

    const float4* A4 = (const float4*)(A + (size_t)b * (NUMPTS * 2));
    const float4* B4 = (const float4*)(Bp + (size_t)b * (NUMPTS * 2));
    const float4* W4 = (const float4*)(W + (size_t)b * NUMPTS);

    // hoist all 20 loads (coalesced: lane t reads 32B contiguous A/B chunks)
    float4 wv[4], av[8], bv[8];
#pragma unroll
    for (int j = 0; j < 4; ++j) wv[j] = W4[t + 16 * j];
#pragma unroll
    for (int j = 0; j < 4; ++j) {
        av[2 * j]     = A4[2 * t + 32 * j];
        av[2 * j + 1] = A4[2 * t + 32 * j + 1];
    }
#pragma unroll
    for (int j = 0; j < 4; ++j) {
        bv[2 * j]     = B4[2 * t + 32 * j];
        bv[2 * j + 1] = B4[2 * t + 32 * j + 1];
    }

    float s1 = 0.f, s2 = 0.f, sax = 0.f, say = 0.f, sbx = 0.f, sby = 0.f;
    float tax = 0.f, tay = 0.f, tbx = 0.f, tby = 0.f;
    float mp = 0.f, mm = 0.f;

#define ACC(ax, ay, bx, by, w) do {                         \
        float _w = (w), _w2 = _w * _w;                      \
        s1 += _w;  s2 += _w2;                               \
        sax += _w * (ax);  say += _w * (ay);                \
        sbx += _w * (bx);  sby += _w * (by);                \
        tax += _w2 * (ax); tay += _w2 * (ay);               \
        tbx += _w2 * (bx); tby += _w2 * (by);               \
        mp += _w2 * ((ax) * (bx) + (ay) * (by));            \
        mm += _w2 * ((ax) * (by) - (ay) * (bx));            \
    } while (0)

#pragma unroll
    for (int j = 0; j < 4; ++j) {
        float4 w4 = wv[j];
        float4 a0 = av[2 * j], a1 = av[2 * j + 1];
        float4 b0 = bv[2 * j], b1 = bv[2 * j + 1];
        ACC(a0.x, a0.y, b0.x, b0.y, w4.x);
        ACC(a0.z, a0.w, b0.z, b0.w, w4.y);
        ACC(a1.x, a1.y, b1.x, b1.y, w4.z);
        ACC(a1.z, a1.w, b1.z, b1.w, w4.w);
    }
#undef ACC

    // butterfly reduce within each 16-lane group (xor 8,4,2,1): 12 values
#pragma unroll
    for (int m = 8; m >= 1; m >>= 1) {
        s1  += __shfl_xor(s1, m);   s2  += __shfl_xor(s2, m);
        sax += __shfl_xor(sax, m);  say += __shfl_xor(say, m);
        sbx += __shfl_xor(sbx, m);  sby += __shfl_xor(sby, m);
        tax += __shfl_xor(tax, m);  tay += __shfl_xor(tay, m);
        tbx += __shfl_xor(tbx, m);  tby += __shfl_xor(tby, m);
        mp  += __shfl_xor(mp, m);   mm  += __shfl_xor(mm, m);
    }

    if (t == 0) {
        float4* Pv = (float4*)P + (size_t)b * 3;
        Pv[0] = make_float4(s2,  sax, say, sbx);
        Pv[1] = make_float4(sby, tax, tay, tbx);
        Pv[2] = make_float4(tby, mp,  mm,  s1);
        S1[b] = s1;   // dense copy: 4 group-leaders/wave write 16B contiguous
    }
}

// ---------------- kernel 2: deterministic global ws = Σ_b s1[b] ----------
__global__ __launch_bounds__(1024) void k_ws(
    const float* __restrict__ S1, float* __restrict__ wsum, int Bn)
{
    const float4* S4 = (const float4*)S1;          // 256 KB contiguous
    float acc = 0.f;
    const int n4 = Bn / 4;
    for (int i = threadIdx.x; i < n4; i += 1024) {
        float4 v = S4[i];
        acc += (v.x + v.y) + (v.z + v.w);
    }
#pragma unroll
    for (int m = 32; m >= 1; m >>= 1) acc += __shfl_xor(acc, m);

    __shared__ float sm[16];
    if ((threadIdx.x & 63) == 0) sm[threadIdx.x >> 6] = acc;
    __syncthreads();
    if (threadIdx.x == 0) {
        float v = 0.f;
#pragma unroll
        for (int i = 0; i < 16; ++i) v += sm[i];
        wsum[0] = v;
    }
}

// ---------------- kernel 3: per-batch closed-form solve -------------------
__global__ __launch_bounds__(256) void k_final(
    const float* __restrict__ P, const float* __restrict__ wsum,
    float* __restrict__ out, int Bn)
{
    const int b = blockIdx.x * 256 + threadIdx.x;
    if (b >= Bn) return;
    const size_t Bs = (size_t)Bn;

    const float4* Pv = (const float4*)P + (size_t)b * 3;
    const float4 p0 = Pv[0], p1 = Pv[1], p2 = Pv[2];

    const float s2  = p0.x;
    const float sax = p0.y, say = p0.z;
    const float sbx = p0.w, sby = p1.x;
    const float tax = p1.y, tay = p1.z;
    const float tbx = p1.w, tby = p2.x;
    const float mp  = p2.y, mm  = p2.z;

    const float inv = 1.0f / wsum[0];
    const float GAx = sax * inv, GAy = say * inv;
    const float GBx = sbx * inv, GBy = sby * inv;

    const float cp = mp - (tax * GBx + tay * GBy) - (GAx * tbx + GAy * tby)
                   + s2 * (GAx * GBx + GAy * GBy);
    const float sp = mm - (tax * GBy - tay * GBx) - (GAx * tby - GAy * tbx)
                   + s2 * (GAx * GBy - GAy * GBx);

    const float theta = atan2f(sp, cp);

    const float r = sqrtf(cp * cp + sp * sp);
    const float c = cp / r, s = sp / r;  // R = [[c,-s],[s,c]]

    const float tx = GBx - (c * GAx - s * GAy);
    const float ty = GBy - (s * GAx + c * GAy);

    out[0 * Bs + b] = theta;
    out[1 * Bs + b] = tx;
    out[2 * Bs + b] = ty;
}

// ---------------- launch ---------------------------------------------------
extern "C" void kernel_launch(void* const* d_in, const int* in_sizes, int n_in,
                              void* d_out, int out_size, void* d_ws, size_t ws_size,
                              hipStream_t stream) {
    const float* A  = (const float*)d_in[0];   // pstA  [B,256,2]
    const float* Bp = (const float*)d_in[1];   // pstB  [B,256,2]
    const float* W  = (const float*)d_in[2];   // weight[B,256,1]
    const int Bn = in_sizes[2] / NUMPTS;       // 65536

    float* P    = (float*)d_ws;                // [Bn][12] floats = 3 MiB
    float* S1   = P + (size_t)Bn * 12;         // dense s1 copy, 256 KB
    float* wsum = S1 + (size_t)Bn;             // +1 scalar
    float* out  = (float*)d_out;               // theta[Bn], tx[Bn], ty[Bn]

    hipLaunchKernelGGL(k_partials, dim3(Bn / 16), dim3(256), 0, stream,
                       A, Bp, W, P, S1, Bn);
    hipLaunchKernelGGL(k_ws, dim3(1), dim3(1024), 0, stream, S1, wsum, Bn);
    hipLaunchKernelGGL(k_final, dim3(Bn / 256), dim3(256), 0, stream,
                       P, wsum, out, Bn);
}

// Round 4
// 73.234 us; speedup vs baseline: 1.4066x; 1.2133x over previous
//
#include <hip/hip_runtime.h>

// Least_Squares_weight: batched weighted 2-D Kabsch with GLOBAL weight sum.
// theta = atan2(H01-H10, H00+H11); t = G_B - R*G_A.
// Per-batch sums (12): s1=Σw, s2=Σw², sa=Σw·a, sb=Σw·b, ta=Σw²·a, tb=Σw²·b,
//   mp=Σw²·(a·b), mm=Σw²·(a×b)_z ;  G = sa/ws, ws = GLOBAL Σ s1.
//
// R4: latency-bound diagnosis (all pipes <20% busy). Fixes:
//  - software pipeline: 4 batches/wave, load batch k+1 while reducing batch k
//  - DPP (VALU) wave reduction: zero DS ops, 12 independent 6-deep chains
//  - dense S1 (k_ws reads 256KB contiguous), 12-float P record

#define NUMPTS 256

// ---- gfx9 DPP full-wave sum; result valid in lanes 48..63 (use lane 63) ---
template <int CTRL, int RM>
__device__ __forceinline__ float dpp_add(float v) {
    int x = __builtin_amdgcn_update_dpp(0, __float_as_int(v), CTRL, RM, 0xF, true);
    return v + __int_as_float(x);
}
__device__ __forceinline__ float red64(float v) {
    v = dpp_add<0xB1,  0xF>(v);   // quad_perm [1,0,3,2]  (xor 1)
    v = dpp_add<0x4E,  0xF>(v);   // quad_perm [2,3,0,1]  (xor 2)
    v = dpp_add<0x141, 0xF>(v);   // row_half_mirror      (xor 4)
    v = dpp_add<0x140, 0xF>(v);   // row_mirror           (xor 8)
    v = dpp_add<0x142, 0xA>(v);   // row_bcast15 -> rows 1,3
    v = dpp_add<0x143, 0xC>(v);   // row_bcast31 -> rows 2,3
    return v;                     // lane 63 holds the full 64-lane sum
}

// P record per batch (12 floats = 3 float4):
// 0:s2 1:sax 2:say 3:sbx | 4:sby 5:tax 6:tay 7:tbx | 8:tby 9:mp 10:mm 11:s1

// ---------------- kernel 1: per-batch partial sums ------------------------
__global__ __launch_bounds__(256) void k_partials(
    const float* __restrict__ A, const float* __restrict__ Bp,
    const float* __restrict__ W, float* __restrict__ P,
    float* __restrict__ S1, int Bn)
{
    const int lane = threadIdx.x & 63;
    const int wave = threadIdx.x >> 6;
    const int bbase = blockIdx.x * 16 + wave * 4;   // 4 consecutive batches/wave

    float4 A0[2], A1[2], B0[2], B1[2], Wv[2];

#define LOADB(buf, b) do {                                                  \
        const float4* A4_ = (const float4*)(A  + (size_t)(b) * (NUMPTS*2)); \
        const float4* B4_ = (const float4*)(Bp + (size_t)(b) * (NUMPTS*2)); \
        const float4* W4_ = (const float4*)(W  + (size_t)(b) * NUMPTS);     \
        A0[buf] = A4_[2*lane]; A1[buf] = A4_[2*lane+1];                     \
        B0[buf] = B4_[2*lane]; B1[buf] = B4_[2*lane+1];                     \
        Wv[buf] = W4_[lane];                                                \
    } while (0)

    LOADB(0, bbase);

#pragma unroll
    for (int k = 0; k < 4; ++k) {
        const int cur = k & 1;
        if (k < 3) LOADB(cur ^ 1, bbase + k + 1);   // prefetch next batch

        const float4 a0 = A0[cur], a1 = A1[cur];
        const float4 b0 = B0[cur], b1 = B1[cur];
        const float4 w4 = Wv[cur];

        float s1 = 0.f, s2 = 0.f, sax = 0.f, say = 0.f, sbx = 0.f, sby = 0.f;
        float tax = 0.f, tay = 0.f, tbx = 0.f, tby = 0.f;
        float mp = 0.f, mm = 0.f;

#define ACC(ax, ay, bx, by, w) do {                         \
            float _w = (w), _w2 = _w * _w;                  \
            s1 += _w;  s2 += _w2;                           \
            sax += _w * (ax);  say += _w * (ay);            \
            sbx += _w * (bx);  sby += _w * (by);            \
            tax += _w2 * (ax); tay += _w2 * (ay);           \
            tbx += _w2 * (bx); tby += _w2 * (by);           \
            mp += _w2 * ((ax) * (bx) + (ay) * (by));        \
            mm += _w2 * ((ax) * (by) - (ay) * (bx));        \
        } while (0)

        ACC(a0.x, a0.y, b0.x, b0.y, w4.x);
        ACC(a0.z, a0.w, b0.z, b0.w, w4.y);
        ACC(a1.x, a1.y, b1.x, b1.y, w4.z);
        ACC(a1.z, a1.w, b1.z, b1.w, w4.w);
#undef ACC

        // pure-VALU wave reduction (no DS pipe); overlaps prefetch latency
        s1  = red64(s1);   s2  = red64(s2);
        sax = red64(sax);  say = red64(say);
        sbx = red64(sbx);  sby = red64(sby);
        tax = red64(tax);  tay = red64(tay);
        tbx = red64(tbx);  tby = red64(tby);
        mp  = red64(mp);   mm  = red64(mm);

        if (lane == 63) {
            const int b = bbase + k;
            float4* Pv = (float4*)P + (size_t)b * 3;
            Pv[0] = make_float4(s2,  sax, say, sbx);
            Pv[1] = make_float4(sby, tax, tay, tbx);
            Pv[2] = make_float4(tby, mp,  mm,  s1);
            S1[b] = s1;
        }
    }
#undef LOADB
}

// ---------------- kernel 2: deterministic global ws = Σ_b s1[b] ----------
__global__ __launch_bounds__(1024) void k_ws(
    const float* __restrict__ S1, float* __restrict__ wsum, int Bn)
{
    const float4* S4 = (const float4*)S1;          // 256 KB contiguous
    float acc = 0.f;
    const int n4 = Bn / 4;
    for (int i = threadIdx.x; i < n4; i += 1024) {
        float4 v = S4[i];
        acc += (v.x + v.y) + (v.z + v.w);
    }
#pragma unroll
    for (int m = 32; m >= 1; m >>= 1) acc += __shfl_xor(acc, m);

    __shared__ float sm[16];
    if ((threadIdx.x & 63) == 0) sm[threadIdx.x >> 6] = acc;
    __syncthreads();
    if (threadIdx.x == 0) {
        float v = 0.f;
#pragma unroll
        for (int i = 0; i < 16; ++i) v += sm[i];
        wsum[0] = v;
    }
}

// ---------------- kernel 3: per-batch closed-form solve -------------------
__global__ __launch_bounds__(256) void k_final(
    const float* __restrict__ P, const float* __restrict__ wsum,
    float* __restrict__ out, int Bn)
{
    const int b = blockIdx.x * 256 + threadIdx.x;
    if (b >= Bn) return;
    const size_t Bs = (size_t)Bn;

    const float4* Pv = (const float4*)P + (size_t)b * 3;
    const float4 p0 = Pv[0], p1 = Pv[1], p2 = Pv[2];

    const float s2  = p0.x;
    const float sax = p0.y, say = p0.z;
    const float sbx = p0.w, sby = p1.x;
    const float tax = p1.y, tay = p1.z;
    const float tbx = p1.w, tby = p2.x;
    const float mp  = p2.y, mm  = p2.z;

    const float inv = 1.0f / wsum[0];
    const float GAx = sax * inv, GAy = say * inv;
    const float GBx = sbx * inv, GBy = sby * inv;

    const float cp = mp - (tax * GBx + tay * GBy) - (GAx * tbx + GAy * tby)
                   + s2 * (GAx * GBx + GAy * GBy);
    const float sp = mm - (tax * GBy - tay * GBx) - (GAx * tby - GAy * tbx)
                   + s2 * (GAx * GBy - GAy * GBx);

    const float theta = atan2f(sp, cp);

    const float r = sqrtf(cp * cp + sp * sp);
    const float c = cp / r, s = sp / r;  // R = [[c,-s],[s,c]]

    const float tx = GBx - (c * GAx - s * GAy);
    const float ty = GBy - (s * GAx + c * GAy);

    out[0 * Bs + b] = theta;
    out[1 * Bs + b] = tx;
    out[2 * Bs + b] = ty;
}

// ---------------- launch ---------------------------------------------------
extern "C" void kernel_launch(void* const* d_in, const int* in_sizes, int n_in,
                              void* d_out, int out_size, void* d_ws, size_t ws_size,
                              hipStream_t stream) {
    const float* A  = (const float*)d_in[0];   // pstA  [B,256,2]
    const float* Bp = (const float*)d_in[1];   // pstB  [B,256,2]
    const float* W  = (const float*)d_in[2];   // weight[B,256,1]
    const int Bn = in_sizes[2] / NUMPTS;       // 65536

    float* P    = (float*)d_ws;                // [Bn][12] floats = 3 MiB
    float* S1   = P + (size_t)Bn * 12;         // dense s1 copy, 256 KB
    float* wsum = S1 + (size_t)Bn;             // +1 scalar
    float* out  = (float*)d_out;               // theta[Bn], tx[Bn], ty[Bn]

    hipLaunchKernelGGL(k_partials, dim3(Bn / 16), dim3(256), 0, stream,
                       A, Bp, W, P, S1, Bn);
    hipLaunchKernelGGL(k_ws, dim3(1), dim3(1024), 0, stream, S1, wsum, Bn);
    hipLaunchKernelGGL(k_final, dim3(Bn / 256), dim3(256), 0, stream,
                       P, wsum, out, Bn);
}

// Round 5
// 68.709 us; speedup vs baseline: 1.4993x; 1.0659x over previous
//
#include <hip/hip_runtime.h>

// Least_Squares_weight: batched weighted 2-D Kabsch with GLOBAL weight sum.
// theta = atan2(H01-H10, H00+H11); t = G_B - R*G_A.
// Per-batch sums (12): s1=Σw, s2=Σw², sa=Σw·a, sb=Σw·b, ta=Σw²·a, tb=Σw²·b,
//   mp=Σw²·(a·b), mm=Σw²·(a×b)_z ;  G = sa/ws, ws = GLOBAL Σ s1.
//
// R5 = R4's double-buffered chunk pipeline + R2's 16-lane-group layout:
//   wave = 4 groups x 16 lanes, group g owns batch bbase+g.
//   j-loop over 4 point-chunks, prefetch j+1 while accumulating j.
//   Reduce = only 4 row-local DPP steps (xor 1,2,4,8), ONCE per wave:
//   96 VALU instr/wave vs R4's 576 (R4 reduced 64-wide per batch, 4x).

#define NUMPTS 256

// one DPP mov+add step; CTRL selects the xor distance (row-local, 16 lanes)
template <int CTRL>
__device__ __forceinline__ float dpp_add16(float v) {
    int x = __builtin_amdgcn_update_dpp(0, __float_as_int(v), CTRL, 0xF, 0xF, true);
    return v + __int_as_float(x);
}
// full 16-lane-group sum (every lane of the group ends with the group sum)
__device__ __forceinline__ float red16(float v) {
    v = dpp_add16<0xB1>(v);    // quad_perm [1,0,3,2]  (xor 1)
    v = dpp_add16<0x4E>(v);    // quad_perm [2,3,0,1]  (xor 2)
    v = dpp_add16<0x141>(v);   // row_half_mirror      (xor 4)
    v = dpp_add16<0x140>(v);   // row_mirror           (xor 8)
    return v;
}

// P record per batch (12 floats = 3 float4):
// 0:s2 1:sax 2:say 3:sbx | 4:sby 5:tax 6:tay 7:tbx | 8:tby 9:mp 10:mm 11:s1

// ---------------- kernel 1: per-batch partial sums ------------------------
__global__ __launch_bounds__(256) void k_partials(
    const float* __restrict__ A, const float* __restrict__ Bp,
    const float* __restrict__ W, float* __restrict__ P,
    float* __restrict__ S1, int Bn)
{
    const int lane = threadIdx.x & 63;
    const int wave = threadIdx.x >> 6;
    const int t = lane & 15;                        // sub-lane within group
    const int b = blockIdx.x * 16 + wave * 4 + (lane >> 4);

    const float4* A4 = (const float4*)(A + (size_t)b * (NUMPTS * 2));
    const float4* B4 = (const float4*)(Bp + (size_t)b * (NUMPTS * 2));
    const float4* W4 = (const float4*)(W + (size_t)b * NUMPTS);

    // double-buffered chunk pipeline: chunk j covers points 64j..64j+63
    // (per lane: 4 points = 2 A-float4 + 2 B-float4 + 1 W-float4)
    float4 a0[2], a1[2], b0[2], b1[2], wv[2];

    a0[0] = A4[2 * t];  a1[0] = A4[2 * t + 1];
    b0[0] = B4[2 * t];  b1[0] = B4[2 * t + 1];
    wv[0] = W4[t];

    float s1 = 0.f, s2 = 0.f, sax = 0.f, say = 0.f, sbx = 0.f, sby = 0.f;
    float tax = 0.f, tay = 0.f, tbx = 0.f, tby = 0.f;
    float mp = 0.f, mm = 0.f;

#define ACC(ax, ay, bx, by, w) do {                         \
        float _w = (w), _w2 = _w * _w;                      \
        s1 += _w;  s2 += _w2;                               \
        sax += _w * (ax);  say += _w * (ay);                \
        sbx += _w * (bx);  sby += _w * (by);                \
        tax += _w2 * (ax); tay += _w2 * (ay);               \
        tbx += _w2 * (bx); tby += _w2 * (by);               \
        mp += _w2 * ((ax) * (bx) + (ay) * (by));            \
        mm += _w2 * ((ax) * (by) - (ay) * (bx));            \
    } while (0)

#pragma unroll
    for (int j = 0; j < 4; ++j) {
        const int cur = j & 1;
        if (j < 3) {                                 // prefetch next chunk
            const int o = 32 * (j + 1);
            a0[cur ^ 1] = A4[2 * t + o];  a1[cur ^ 1] = A4[2 * t + o + 1];
            b0[cur ^ 1] = B4[2 * t + o];  b1[cur ^ 1] = B4[2 * t + o + 1];
            wv[cur ^ 1] = W4[t + 16 * (j + 1)];
        }
        const float4 ca0 = a0[cur], ca1 = a1[cur];
        const float4 cb0 = b0[cur], cb1 = b1[cur];
        const float4 cw  = wv[cur];
        ACC(ca0.x, ca0.y, cb0.x, cb0.y, cw.x);
        ACC(ca0.z, ca0.w, cb0.z, cb0.w, cw.y);
        ACC(ca1.x, ca1.y, cb1.x, cb1.y, cw.z);
        ACC(ca1.z, ca1.w, cb1.z, cb1.w, cw.w);
    }
#undef ACC

    // 16-lane-group reduction, once per wave: 4 DPP steps x 12 quantities
    s1  = red16(s1);   s2  = red16(s2);
    sax = red16(sax);  say = red16(say);
    sbx = red16(sbx);  sby = red16(sby);
    tax = red16(tax);  tay = red16(tay);
    tbx = red16(tbx);  tby = red16(tby);
    mp  = red16(mp);   mm  = red16(mm);

    if (t == 0) {
        float4* Pv = (float4*)P + (size_t)b * 3;
        Pv[0] = make_float4(s2,  sax, say, sbx);
        Pv[1] = make_float4(sby, tax, tay, tbx);
        Pv[2] = make_float4(tby, mp,  mm,  s1);
        S1[b] = s1;
    }
}

// ---------------- kernel 2: deterministic global ws = Σ_b s1[b] ----------
__global__ __launch_bounds__(1024) void k_ws(
    const float* __restrict__ S1, float* __restrict__ wsum, int Bn)
{
    const float4* S4 = (const float4*)S1;          // 256 KB contiguous
    float acc = 0.f;
    const int n4 = Bn / 4;
    for (int i = threadIdx.x; i < n4; i += 1024) {
        float4 v = S4[i];
        acc += (v.x + v.y) + (v.z + v.w);
    }
#pragma unroll
    for (int m = 32; m >= 1; m >>= 1) acc += __shfl_xor(acc, m);

    __shared__ float sm[16];
    if ((threadIdx.x & 63) == 0) sm[threadIdx.x >> 6] = acc;
    __syncthreads();
    if (threadIdx.x == 0) {
        float v = 0.f;
#pragma unroll
        for (int i = 0; i < 16; ++i) v += sm[i];
        wsum[0] = v;
    }
}

// ---------------- kernel 3: per-batch closed-form solve -------------------
__global__ __launch_bounds__(256) void k_final(
    const float* __restrict__ P, const float* __restrict__ wsum,
    float* __restrict__ out, int Bn)
{
    const int b = blockIdx.x * 256 + threadIdx.x;
    if (b >= Bn) return;
    const size_t Bs = (size_t)Bn;

    const float4* Pv = (const float4*)P + (size_t)b * 3;
    const float4 p0 = Pv[0], p1 = Pv[1], p2 = Pv[2];

    const float s2  = p0.x;
    const float sax = p0.y, say = p0.z;
    const float sbx = p0.w, sby = p1.x;
    const float tax = p1.y, tay = p1.z;
    const float tbx = p1.w, tby = p2.x;
    const float mp  = p2.y, mm  = p2.z;

    const float inv = 1.0f / wsum[0];
    const float GAx = sax * inv, GAy = say * inv;
    const float GBx = sbx * inv, GBy = sby * inv;

    const float cp = mp - (tax * GBx + tay * GBy) - (GAx * tbx + GAy * tby)
                   + s2 * (GAx * GBx + GAy * GBy);
    const float sp = mm - (tax * GBy - tay * GBx) - (GAx * tby - GAy * tbx)
                   + s2 * (GAx * GBy - GAy * GBx);

    const float theta = atan2f(sp, cp);

    const float r = sqrtf(cp * cp + sp * sp);
    const float c = cp / r, s = sp / r;  // R = [[c,-s],[s,c]]

    const float tx = GBx - (c * GAx - s * GAy);
    const float ty = GBy - (s * GAx + c * GAy);

    out[0 * Bs + b] = theta;
    out[1 * Bs + b] = tx;
    out[2 * Bs + b] = ty;
}

// ---------------- launch ---------------------------------------------------
extern "C" void kernel_launch(void* const* d_in, const int* in_sizes, int n_in,
                              void* d_out, int out_size, void* d_ws, size_t ws_size,
                              hipStream_t stream) {
    const float* A  = (const float*)d_in[0];   // pstA  [B,256,2]
    const float* Bp = (const float*)d_in[1];   // pstB  [B,256,2]
    const float* W  = (const float*)d_in[2];   // weight[B,256,1]
    const int Bn = in_sizes[2] / NUMPTS;       // 65536

    float* P    = (float*)d_ws;                // [Bn][12] floats = 3 MiB
    float* S1   = P + (size_t)Bn * 12;         // dense s1 copy, 256 KB
    float* wsum = S1 + (size_t)Bn;             // +1 scalar
    float* out  = (float*)d_out;               // theta[Bn], tx[Bn], ty[Bn]

    hipLaunchKernelGGL(k_partials, dim3(Bn / 16), dim3(256), 0, stream,
                       A, Bp, W, P, S1, Bn);
    hipLaunchKernelGGL(k_ws, dim3(1), dim3(1024), 0, stream, S1, wsum, Bn);
    hipLaunchKernelGGL(k_final, dim3(Bn / 256), dim3(256), 0, stream,
                       P, wsum, out, Bn);
}